// Round 2
// baseline (1504.711 us; speedup 1.0000x reference)
//
#include <hip/hip_runtime.h>

// Problem constants (match reference setup_inputs)
#define NODES 50000
#define NEDGE 1600000
#define ND 64      // NODE_DIM
#define ED 32      // EDGE_DIM
#define HID 64     // HIDDEN
#define IN_DIM 96  // ND + ED

#define TILE_E 64
#define STA 68     // padded LDS stride for transposed msg tile (68*4B = 272B, 16B aligned)

// ---------------- K0: zero accumulators ----------------
__global__ void zero_kernel(float* __restrict__ out, float* __restrict__ cnt) {
    int i = blockIdx.x * blockDim.x + threadIdx.x;
    int stride = gridDim.x * blockDim.x;
    const int total = NODES * ND;
    for (int idx = i; idx < total; idx += stride) out[idx] = 0.0f;
    for (int idx = i; idx < NODES; idx += stride) cnt[idx] = 0.0f;
}

// ---------------- K1: per-edge MLP + atomic scatter-sum ----------------
// edge_index is int32 on device (harness converts integer inputs to int): [2][E], dst = row 1.
__global__ __launch_bounds__(256, 2)
void edge_mlp_kernel(const float* __restrict__ x,
                     const int* __restrict__ edge_index,
                     const float* __restrict__ edge_attr,
                     const float* __restrict__ W1, const float* __restrict__ b1,
                     const float* __restrict__ W2, const float* __restrict__ b2,
                     float* __restrict__ out_sum, float* __restrict__ cnt)
{
    __shared__ __align__(16) float At[IN_DIM * STA];    // msg tile, transposed [k][e]; reused for h^T
    __shared__ __align__(16) float W1l[IN_DIM * HID];   // [k][j]
    __shared__ __align__(16) float W2l[HID * ND];       // [k][j]
    __shared__ float b1l[HID], b2l[ND];
    __shared__ int dstl[TILE_E];

    const int t = threadIdx.x;

    // stage weights once per block (persistent blocks)
    {
        const float4* w1v = (const float4*)W1;   // 1536 float4
        float4* w1s = (float4*)W1l;
        for (int i = t; i < IN_DIM * HID / 4; i += 256) w1s[i] = w1v[i];
        const float4* w2v = (const float4*)W2;   // 1024 float4
        float4* w2s = (float4*)W2l;
        for (int i = t; i < HID * ND / 4; i += 256) w2s[i] = w2v[i];
        if (t < HID) b1l[t] = b1[t];
        if (t < ND)  b2l[t] = b2[t];
    }

    const int tr = t >> 4;          // 0..15 -> edge group
    const int tc = t & 15;          // 0..15 -> output-col group
    const int e0 = tr * 4;
    const int j0 = tc * 4;

    const int ntiles = NEDGE / TILE_E;   // 25000 exactly
    for (int tile = blockIdx.x; tile < ntiles; tile += gridDim.x) {
        const int eb = tile * TILE_E;

        __syncthreads();   // protect At / dstl from previous iteration readers

        // ---- stage dst + counts ----
        if (t < TILE_E) {
            int d = edge_index[NEDGE + eb + t];
            dstl[t] = d;
            atomicAdd(&cnt[d], 1.0f);
        }

        // ---- stage gathered x rows + edge_attr, transposed into At[k][e] ----
        {
            const int e = t >> 2;           // 0..63
            const int c = t & 3;            // 0..3
            const int drow = edge_index[NEDGE + eb + e];
            const float* xr = x + (long long)drow * ND;
            #pragma unroll
            for (int it = 0; it < 4; ++it) {
                const int c4 = c + it * 4;      // float4 chunk 0..15
                float4 v = *(const float4*)(xr + c4 * 4);
                At[(c4 * 4 + 0) * STA + e] = v.x;
                At[(c4 * 4 + 1) * STA + e] = v.y;
                At[(c4 * 4 + 2) * STA + e] = v.z;
                At[(c4 * 4 + 3) * STA + e] = v.w;
            }
            const float* er = edge_attr + (long long)(eb + e) * ED;
            #pragma unroll
            for (int it = 0; it < 2; ++it) {
                const int c2 = c * 2 + it;      // float4 chunk 0..7
                float4 v = *(const float4*)(er + c2 * 4);
                At[(ND + c2 * 4 + 0) * STA + e] = v.x;
                At[(ND + c2 * 4 + 1) * STA + e] = v.y;
                At[(ND + c2 * 4 + 2) * STA + e] = v.z;
                At[(ND + c2 * 4 + 3) * STA + e] = v.w;
            }
        }
        __syncthreads();

        // ---- GEMM1: h[e][j] = relu(msg[e][:] @ W1[:, j] + b1) ----
        float acc[4][4];
        #pragma unroll
        for (int i = 0; i < 4; ++i)
            #pragma unroll
            for (int j = 0; j < 4; ++j) acc[i][j] = 0.0f;

        #pragma unroll 8
        for (int k = 0; k < IN_DIM; ++k) {
            float4 a = *(const float4*)&At[k * STA + e0];
            float4 b = *(const float4*)&W1l[k * HID + j0];
            float av[4] = {a.x, a.y, a.z, a.w};
            float bv[4] = {b.x, b.y, b.z, b.w};
            #pragma unroll
            for (int i = 0; i < 4; ++i)
                #pragma unroll
                for (int j = 0; j < 4; ++j)
                    acc[i][j] = fmaf(av[i], bv[j], acc[i][j]);
        }
        __syncthreads();   // all GEMM1 reads of At complete

        // ---- bias + relu, write h^T back into At[j][e] ----
        #pragma unroll
        for (int jj = 0; jj < 4; ++jj) {
            const float bb = b1l[j0 + jj];
            float4 v;
            v.x = fmaxf(acc[0][jj] + bb, 0.0f);
            v.y = fmaxf(acc[1][jj] + bb, 0.0f);
            v.z = fmaxf(acc[2][jj] + bb, 0.0f);
            v.w = fmaxf(acc[3][jj] + bb, 0.0f);
            *(float4*)&At[(j0 + jj) * STA + e0] = v;
        }
        __syncthreads();

        // ---- GEMM2: m[e][d] = relu(h[e][:] @ W2[:, d] + b2) ----
        float acc2[4][4];
        #pragma unroll
        for (int i = 0; i < 4; ++i)
            #pragma unroll
            for (int j = 0; j < 4; ++j) acc2[i][j] = 0.0f;

        #pragma unroll 8
        for (int k = 0; k < HID; ++k) {
            float4 a = *(const float4*)&At[k * STA + e0];
            float4 b = *(const float4*)&W2l[k * ND + j0];
            float av[4] = {a.x, a.y, a.z, a.w};
            float bv[4] = {b.x, b.y, b.z, b.w};
            #pragma unroll
            for (int i = 0; i < 4; ++i)
                #pragma unroll
                for (int j = 0; j < 4; ++j)
                    acc2[i][j] = fmaf(av[i], bv[j], acc2[i][j]);
        }

        // ---- scatter-add into out_sum ----
        #pragma unroll
        for (int i = 0; i < 4; ++i) {
            const int d = dstl[e0 + i];
            float* orow = out_sum + (long long)d * ND + j0;
            #pragma unroll
            for (int jj = 0; jj < 4; ++jj) {
                float m = fmaxf(acc2[i][jj] + b2l[j0 + jj], 0.0f);
                atomicAdd(orow + jj, m);
            }
        }
    }
}

// ---------------- K2: finalize out = sum/max(cnt,1) + x ----------------
__global__ void finalize_kernel(const float* __restrict__ x,
                                const float* __restrict__ cnt,
                                float* __restrict__ out)
{
    int i = blockIdx.x * blockDim.x + threadIdx.x;
    int stride = gridDim.x * blockDim.x;
    const int total4 = NODES * ND / 4;
    for (int idx = i; idx < total4; idx += stride) {
        const int n = idx / (ND / 4);
        const float inv = 1.0f / fmaxf(cnt[n], 1.0f);
        float4 s = ((const float4*)out)[idx];
        float4 xv = ((const float4*)x)[idx];
        float4 r;
        r.x = s.x * inv + xv.x;
        r.y = s.y * inv + xv.y;
        r.z = s.z * inv + xv.z;
        r.w = s.w * inv + xv.w;
        ((float4*)out)[idx] = r;
    }
}

extern "C" void kernel_launch(void* const* d_in, const int* in_sizes, int n_in,
                              void* d_out, int out_size, void* d_ws, size_t ws_size,
                              hipStream_t stream) {
    const float* x  = (const float*)d_in[0];
    const int*   ei = (const int*)d_in[1];     // int64 in reference -> int32 on device
    const float* ea = (const float*)d_in[2];
    const float* W1 = (const float*)d_in[3];
    const float* b1 = (const float*)d_in[4];
    const float* W2 = (const float*)d_in[5];
    const float* b2 = (const float*)d_in[6];
    float* out = (float*)d_out;
    float* cnt = (float*)d_ws;   // NODES floats of scratch

    hipLaunchKernelGGL(zero_kernel, dim3(2048), dim3(256), 0, stream, out, cnt);
    hipLaunchKernelGGL(edge_mlp_kernel, dim3(512), dim3(256), 0, stream,
                       x, ei, ea, W1, b1, W2, b2, out, cnt);
    hipLaunchKernelGGL(finalize_kernel, dim3(1600), dim3(256), 0, stream, x, cnt, out);
}

// Round 3
// 814.595 us; speedup vs baseline: 1.8472x; 1.8472x over previous
//
#include <hip/hip_runtime.h>

// Problem constants (match reference setup_inputs)
#define NODES 50000
#define NEDGE 1600000
#define ND 64      // NODE_DIM
#define ED 32      // EDGE_DIM
#define HID 64     // HIDDEN
#define IN_DIM 96  // ND + ED

#define TILE_E 64
#define STA 68     // padded LDS stride for transposed msg tile
#define MTS 65     // odd stride for m-tile (column reads conflict-free)

// ---------------- K0: zero out accumulator + counts ----------------
__global__ void zero_kernel(float* __restrict__ out, int* __restrict__ cnt) {
    int i = blockIdx.x * blockDim.x + threadIdx.x;
    int stride = gridDim.x * blockDim.x;
    const int total = NODES * ND;
    for (int idx = i; idx < total; idx += stride) out[idx] = 0.0f;
    for (int idx = i; idx < NODES; idx += stride) cnt[idx] = 0;
}

// ---------------- K1: histogram of dst ----------------
__global__ void hist_kernel(const int* __restrict__ ei, int* __restrict__ cnt) {
    int i = blockIdx.x * blockDim.x + threadIdx.x;
    int stride = gridDim.x * blockDim.x;
    for (int e = i; e < NEDGE; e += stride)
        atomicAdd(&cnt[ei[NEDGE + e]], 1);
}

// ---------------- K2: exclusive prefix sum over 50K counts (1 block) ----------------
#define SCAN_T 1024
#define SCAN_CH ((NODES + SCAN_T - 1) / SCAN_T)   // 49
__global__ void scan_kernel(const int* __restrict__ cnt, int* __restrict__ offs,
                            int* __restrict__ cursor) {
    __shared__ int part[SCAN_T];
    const int t = threadIdx.x;
    const int beg = t * SCAN_CH;
    const int end = min(beg + SCAN_CH, NODES);
    int s = 0;
    for (int i = beg; i < end; ++i) s += cnt[i];
    part[t] = s;
    __syncthreads();
    // Hillis-Steele inclusive scan
    for (int d = 1; d < SCAN_T; d <<= 1) {
        int v = (t >= d) ? part[t - d] : 0;
        __syncthreads();
        part[t] += v;
        __syncthreads();
    }
    int run = (t > 0) ? part[t - 1] : 0;   // exclusive prefix of this chunk
    for (int i = beg; i < end; ++i) {
        offs[i] = run;
        cursor[i] = run;
        run += cnt[i];
    }
    if (t == SCAN_T - 1) offs[NODES] = part[SCAN_T - 1];
}

// ---------------- K3: bucket-scatter edge ids (CSR perm) ----------------
__global__ void bucket_kernel(const int* __restrict__ ei, int* __restrict__ cursor,
                              int* __restrict__ perm, int* __restrict__ dsts) {
    int i = blockIdx.x * blockDim.x + threadIdx.x;
    int stride = gridDim.x * blockDim.x;
    for (int e = i; e < NEDGE; e += stride) {
        int d = ei[NEDGE + e];
        int pos = atomicAdd(&cursor[d], 1);
        perm[pos] = e;
        dsts[pos] = d;
    }
}

// ---------------- K4: per-edge MLP (64-edge tiles) ----------------
// SORTED=true: edges in CSR order (perm/dsts), segmented-run scatter via LDS.
// SORTED=false: natural order, direct global atomics (ws-too-small fallback).
template <bool SORTED>
__global__ __launch_bounds__(256, 2)
void edge_mlp_kernel(const float* __restrict__ x,
                     const int* __restrict__ edge_index,
                     const float* __restrict__ edge_attr,
                     const float* __restrict__ W1, const float* __restrict__ b1,
                     const float* __restrict__ W2, const float* __restrict__ b2,
                     const int* __restrict__ perm, const int* __restrict__ dsts,
                     float* __restrict__ out_sum)
{
    __shared__ __align__(16) float At[IN_DIM * STA];    // msg^T tile; reused for h^T and m-tile
    __shared__ __align__(16) float W1l[IN_DIM * HID];
    __shared__ __align__(16) float W2l[HID * ND];
    __shared__ float b1l[HID], b2l[ND];
    __shared__ int dstl[TILE_E];

    const int t = threadIdx.x;

    { // stage weights once (persistent blocks)
        const float4* w1v = (const float4*)W1;
        float4* w1s = (float4*)W1l;
        for (int i = t; i < IN_DIM * HID / 4; i += 256) w1s[i] = w1v[i];
        const float4* w2v = (const float4*)W2;
        float4* w2s = (float4*)W2l;
        for (int i = t; i < HID * ND / 4; i += 256) w2s[i] = w2v[i];
        if (t < HID) b1l[t] = b1[t];
        if (t < ND)  b2l[t] = b2[t];
    }

    const int tr = t >> 4;          // 0..15 edge group
    const int tc = t & 15;          // 0..15 col group
    const int e0 = tr * 4;
    const int j0 = tc * 4;

    const int ntiles = NEDGE / TILE_E;   // 25000
    for (int tile = blockIdx.x; tile < ntiles; tile += gridDim.x) {
        const int eb = tile * TILE_E;

        __syncthreads();   // protect At/dstl from previous iteration readers

        if (t < TILE_E)
            dstl[t] = SORTED ? dsts[eb + t] : edge_index[NEDGE + eb + t];

        { // stage gathered x rows + edge_attr, transposed into At[k][e]
            const int e = t >> 2;
            const int c = t & 3;
            const int drow = SORTED ? dsts[eb + e] : edge_index[NEDGE + eb + e];
            const int eg   = SORTED ? perm[eb + e] : (eb + e);
            const float* xr = x + (long long)drow * ND;
            #pragma unroll
            for (int it = 0; it < 4; ++it) {
                const int c4 = c + it * 4;
                float4 v = *(const float4*)(xr + c4 * 4);
                At[(c4 * 4 + 0) * STA + e] = v.x;
                At[(c4 * 4 + 1) * STA + e] = v.y;
                At[(c4 * 4 + 2) * STA + e] = v.z;
                At[(c4 * 4 + 3) * STA + e] = v.w;
            }
            const float* er = edge_attr + (long long)eg * ED;
            #pragma unroll
            for (int it = 0; it < 2; ++it) {
                const int c2 = c * 2 + it;
                float4 v = *(const float4*)(er + c2 * 4);
                At[(ND + c2 * 4 + 0) * STA + e] = v.x;
                At[(ND + c2 * 4 + 1) * STA + e] = v.y;
                At[(ND + c2 * 4 + 2) * STA + e] = v.z;
                At[(ND + c2 * 4 + 3) * STA + e] = v.w;
            }
        }
        __syncthreads();

        // ---- GEMM1: h = relu(msg @ W1 + b1) ----
        float acc[4][4];
        #pragma unroll
        for (int i = 0; i < 4; ++i)
            #pragma unroll
            for (int j = 0; j < 4; ++j) acc[i][j] = 0.0f;

        #pragma unroll 8
        for (int k = 0; k < IN_DIM; ++k) {
            float4 a = *(const float4*)&At[k * STA + e0];
            float4 b = *(const float4*)&W1l[k * HID + j0];
            float av[4] = {a.x, a.y, a.z, a.w};
            float bv[4] = {b.x, b.y, b.z, b.w};
            #pragma unroll
            for (int i = 0; i < 4; ++i)
                #pragma unroll
                for (int j = 0; j < 4; ++j)
                    acc[i][j] = fmaf(av[i], bv[j], acc[i][j]);
        }
        __syncthreads();

        // ---- bias + relu, write h^T back into At[j][e] ----
        #pragma unroll
        for (int jj = 0; jj < 4; ++jj) {
            const float bb = b1l[j0 + jj];
            float4 v;
            v.x = fmaxf(acc[0][jj] + bb, 0.0f);
            v.y = fmaxf(acc[1][jj] + bb, 0.0f);
            v.z = fmaxf(acc[2][jj] + bb, 0.0f);
            v.w = fmaxf(acc[3][jj] + bb, 0.0f);
            *(float4*)&At[(j0 + jj) * STA + e0] = v;
        }
        __syncthreads();

        // ---- GEMM2: m = relu(h @ W2 + b2) ----
        float acc2[4][4];
        #pragma unroll
        for (int i = 0; i < 4; ++i)
            #pragma unroll
            for (int j = 0; j < 4; ++j) acc2[i][j] = 0.0f;

        #pragma unroll 8
        for (int k = 0; k < HID; ++k) {
            float4 a = *(const float4*)&At[k * STA + e0];
            float4 b = *(const float4*)&W2l[k * ND + j0];
            float av[4] = {a.x, a.y, a.z, a.w};
            float bv[4] = {b.x, b.y, b.z, b.w};
            #pragma unroll
            for (int i = 0; i < 4; ++i)
                #pragma unroll
                for (int j = 0; j < 4; ++j)
                    acc2[i][j] = fmaf(av[i], bv[j], acc2[i][j]);
        }

        if constexpr (SORTED) {
            __syncthreads();   // GEMM2 reads of At complete before m-tile overwrite
            float* Mt = At;    // reuse: [TILE_E][MTS]
            #pragma unroll
            for (int i = 0; i < 4; ++i)
                #pragma unroll
                for (int jj = 0; jj < 4; ++jj)
                    Mt[(e0 + i) * MTS + j0 + jj] =
                        fmaxf(acc2[i][jj] + b2l[j0 + jj], 0.0f);
            __syncthreads();

            // segmented run-merge scatter: thread = (col, 16-row window)
            const int c = t & 63;
            const int q = t >> 6;          // 0..3
            const int r0 = q * 16;
            int cur = dstl[r0];
            float s = 0.0f;
            #pragma unroll 4
            for (int r = r0; r < r0 + 16; ++r) {
                const int d = dstl[r];
                if (d != cur) {
                    atomicAdd(&out_sum[(long long)cur * ND + c], s);
                    s = 0.0f; cur = d;
                }
                s += Mt[r * MTS + c];
            }
            atomicAdd(&out_sum[(long long)cur * ND + c], s);
        } else {
            #pragma unroll
            for (int i = 0; i < 4; ++i) {
                const int d = dstl[e0 + i];
                float* orow = out_sum + (long long)d * ND + j0;
                #pragma unroll
                for (int jj = 0; jj < 4; ++jj) {
                    float m = fmaxf(acc2[i][jj] + b2l[j0 + jj], 0.0f);
                    atomicAdd(orow + jj, m);
                }
            }
        }
    }
}

// ---------------- K5: finalize out = sum/max(cnt,1) + x ----------------
__global__ void finalize_kernel(const float* __restrict__ x,
                                const int* __restrict__ cnt,
                                float* __restrict__ out)
{
    int i = blockIdx.x * blockDim.x + threadIdx.x;
    int stride = gridDim.x * blockDim.x;
    const int total4 = NODES * ND / 4;
    for (int idx = i; idx < total4; idx += stride) {
        const int n = idx / (ND / 4);
        const float inv = 1.0f / fmaxf((float)cnt[n], 1.0f);
        float4 s = ((const float4*)out)[idx];
        float4 xv = ((const float4*)x)[idx];
        float4 r;
        r.x = s.x * inv + xv.x;
        r.y = s.y * inv + xv.y;
        r.z = s.z * inv + xv.z;
        r.w = s.w * inv + xv.w;
        ((float4*)out)[idx] = r;
    }
}

extern "C" void kernel_launch(void* const* d_in, const int* in_sizes, int n_in,
                              void* d_out, int out_size, void* d_ws, size_t ws_size,
                              hipStream_t stream) {
    const float* x  = (const float*)d_in[0];
    const int*   ei = (const int*)d_in[1];     // int64 in reference -> int32 on device
    const float* ea = (const float*)d_in[2];
    const float* W1 = (const float*)d_in[3];
    const float* b1 = (const float*)d_in[4];
    const float* W2 = (const float*)d_in[5];
    const float* b2 = (const float*)d_in[6];
    float* out = (float*)d_out;

    // d_ws layout (ints): cnt[N] | offs[N+1] | cursor[N] | perm[E] | dsts[E]
    int* cnt    = (int*)d_ws;
    int* offs   = cnt + NODES;
    int* cursor = offs + NODES + 1;
    int* perm   = cursor + NODES;
    int* dsts   = perm + NEDGE;
    const size_t need = (size_t)(3 * NODES + 1 + 2 * NEDGE) * sizeof(int);

    hipLaunchKernelGGL(zero_kernel, dim3(2048), dim3(256), 0, stream, out, cnt);
    hipLaunchKernelGGL(hist_kernel, dim3(2048), dim3(256), 0, stream, ei, cnt);

    if (ws_size >= need) {
        hipLaunchKernelGGL(scan_kernel, dim3(1), dim3(SCAN_T), 0, stream, cnt, offs, cursor);
        hipLaunchKernelGGL(bucket_kernel, dim3(2048), dim3(256), 0, stream, ei, cursor, perm, dsts);
        hipLaunchKernelGGL((edge_mlp_kernel<true>), dim3(512), dim3(256), 0, stream,
                           x, ei, ea, W1, b1, W2, b2, perm, dsts, out);
    } else {
        hipLaunchKernelGGL((edge_mlp_kernel<false>), dim3(512), dim3(256), 0, stream,
                           x, ei, ea, W1, b1, W2, b2, (const int*)nullptr, (const int*)nullptr, out);
    }
    hipLaunchKernelGGL(finalize_kernel, dim3(1600), dim3(256), 0, stream, x, cnt, out);
}

// Round 4
// 469.088 us; speedup vs baseline: 3.2077x; 1.7366x over previous
//
#include <hip/hip_runtime.h>

// Problem constants (match reference setup_inputs)
#define NODES 50000
#define NEDGE 1600000
#define ND 64      // NODE_DIM
#define ED 32      // EDGE_DIM
#define HID 64     // HIDDEN
#define IN_DIM 96  // ND + ED

#define TILE_E 64
#define MSG_LD 104   // bf16 elems/row: 96+8 pad -> 208 B rows (16B aligned, 2-way banks on b128)
#define H_LD   72    // bf16 elems/row: 64+8 pad -> 144 B rows
#define MT_LD  65    // f32 elems/row for m-tile (odd -> conflict-free column reads)

typedef __bf16 bf16_t;
typedef __bf16 bf16x4_t __attribute__((ext_vector_type(4)));
typedef __bf16 bf16x8_t __attribute__((ext_vector_type(8)));
typedef float  f32x4_t  __attribute__((ext_vector_type(4)));

// ---------------- K0: zero out accumulator + counts ----------------
__global__ void zero_kernel(float* __restrict__ out, int* __restrict__ cnt) {
    int i = blockIdx.x * blockDim.x + threadIdx.x;
    int stride = gridDim.x * blockDim.x;
    const int total = NODES * ND;
    for (int idx = i; idx < total; idx += stride) out[idx] = 0.0f;
    for (int idx = i; idx < NODES; idx += stride) cnt[idx] = 0;
}

// ---------------- K1: histogram of dst ----------------
__global__ void hist_kernel(const int* __restrict__ ei, int* __restrict__ cnt) {
    int i = blockIdx.x * blockDim.x + threadIdx.x;
    int stride = gridDim.x * blockDim.x;
    for (int e = i; e < NEDGE; e += stride)
        atomicAdd(&cnt[ei[NEDGE + e]], 1);
}

// ---------------- K2: exclusive prefix sum over 50K counts (1 block) ----------------
#define SCAN_T 1024
#define SCAN_CH ((NODES + SCAN_T - 1) / SCAN_T)   // 49
__global__ void scan_kernel(const int* __restrict__ cnt, int* __restrict__ offs,
                            int* __restrict__ cursor) {
    __shared__ int part[SCAN_T];
    const int t = threadIdx.x;
    const int beg = t * SCAN_CH;
    const int end = min(beg + SCAN_CH, NODES);
    int s = 0;
    for (int i = beg; i < end; ++i) s += cnt[i];
    part[t] = s;
    __syncthreads();
    for (int d = 1; d < SCAN_T; d <<= 1) {
        int v = (t >= d) ? part[t - d] : 0;
        __syncthreads();
        part[t] += v;
        __syncthreads();
    }
    int run = (t > 0) ? part[t - 1] : 0;
    for (int i = beg; i < end; ++i) {
        offs[i] = run;
        cursor[i] = run;
        run += cnt[i];
    }
    if (t == SCAN_T - 1) offs[NODES] = part[SCAN_T - 1];
}

// ---------------- K3: bucket-scatter edge ids (CSR perm) ----------------
__global__ void bucket_kernel(const int* __restrict__ ei, int* __restrict__ cursor,
                              int* __restrict__ perm, int* __restrict__ dsts) {
    int i = blockIdx.x * blockDim.x + threadIdx.x;
    int stride = gridDim.x * blockDim.x;
    for (int e = i; e < NEDGE; e += stride) {
        int d = ei[NEDGE + e];
        int pos = atomicAdd(&cursor[d], 1);
        perm[pos] = e;
        dsts[pos] = d;
    }
}

// ---------------- K4: per-edge MLP via bf16 MFMA (64-edge tiles, CSR order) ----------------
// Wave-private tile rows: wave w owns edges 16w..16w+15 of each tile (staging,
// GEMM A-rows, h rows, Mt rows, merge window all line up) -> 3 barriers/tile.
__global__ __launch_bounds__(256, 2)
void edge_mlp_mfma(const float* __restrict__ x,
                   const float* __restrict__ edge_attr,
                   const float* __restrict__ W1, const float* __restrict__ b1,
                   const float* __restrict__ W2, const float* __restrict__ b2,
                   const int* __restrict__ perm, const int* __restrict__ dsts,
                   float* __restrict__ out_sum)
{
    constexpr int SMEM_MAIN = TILE_E * MSG_LD * 2 + TILE_E * H_LD * 2; // 22528 B
    constexpr int SMEM_MT   = TILE_E * MT_LD * 4;                      // 16640 B
    __shared__ __align__(16) char smem[SMEM_MAIN > SMEM_MT ? SMEM_MAIN : SMEM_MT];
    __shared__ int dstl[TILE_E];

    bf16_t* msgS = (bf16_t*)smem;                               // [64][MSG_LD]
    bf16_t* hS   = (bf16_t*)(smem + TILE_E * MSG_LD * 2);       // [64][H_LD]
    float*  Mt   = (float*)smem;                                // [64][MT_LD] (scatter phase)

    const int t    = threadIdx.x;
    const int lane = t & 63;
    const int w    = t >> 6;         // wave id 0..3
    const int col  = lane & 15;      // MFMA col / A-row selector
    const int kq   = lane >> 4;      // 0..3: k-quarter

    // ---- one-time: transpose W1,W2 into LDS (bf16) ----
    for (int i = t; i < IN_DIM * HID / 4; i += 256) {
        float4 v = ((const float4*)W1)[i];
        int k = i >> 4, j4 = (i & 15) * 4;      // W1[k][j4..j4+3]
        msgS[(j4 + 0) * MSG_LD + k] = (bf16_t)v.x;
        msgS[(j4 + 1) * MSG_LD + k] = (bf16_t)v.y;
        msgS[(j4 + 2) * MSG_LD + k] = (bf16_t)v.z;
        msgS[(j4 + 3) * MSG_LD + k] = (bf16_t)v.w;
    }
    for (int i = t; i < HID * ND / 4; i += 256) {
        float4 v = ((const float4*)W2)[i];
        int k = i >> 4, j4 = (i & 15) * 4;
        hS[(j4 + 0) * H_LD + k] = (bf16_t)v.x;
        hS[(j4 + 1) * H_LD + k] = (bf16_t)v.y;
        hS[(j4 + 2) * H_LD + k] = (bf16_t)v.z;
        hS[(j4 + 3) * H_LD + k] = (bf16_t)v.w;
    }
    __syncthreads();

    // ---- hoist loop-invariant B-fragments + biases to registers ----
    // B-frag lane layout (16x16x32): col = lane&15, k = (lane>>4)*8 + j (8 contiguous)
    bf16x8_t w1f[4][3];   // [ntile][kstep]
    bf16x8_t w2f[4][2];
    float b1r[4], b2r[4];
    #pragma unroll
    for (int nt = 0; nt < 4; ++nt) {
        const int cn = col + 16 * nt;
        b1r[nt] = b1[cn];
        b2r[nt] = b2[cn];
        #pragma unroll
        for (int kk = 0; kk < 3; ++kk)
            w1f[nt][kk] = *(const bf16x8_t*)&msgS[cn * MSG_LD + kk * 32 + kq * 8];
        #pragma unroll
        for (int kk = 0; kk < 2; ++kk)
            w2f[nt][kk] = *(const bf16x8_t*)&hS[cn * H_LD + kk * 32 + kq * 8];
    }
    __syncthreads();   // weights consumed; smem free for tiles

    const int ntiles = NEDGE / TILE_E;   // 25000
    for (int tile = blockIdx.x; tile < ntiles; tile += gridDim.x) {
        const int eb = tile * TILE_E;
        __syncthreads();   // smem + dstl free of previous tile's readers

        if (t < TILE_E) dstl[t] = dsts[eb + t];

        // ---- stage msg tile (bf16): rows wave-private ----
        {
            const int e = t >> 2, c = t & 3;
            const int drow = dsts[eb + e];
            const int eg   = perm[eb + e];
            const float4* xr = (const float4*)(x + (size_t)drow * ND);
            #pragma unroll
            for (int it = 0; it < 4; ++it) {
                const int c4 = c + it * 4;
                float4 v = xr[c4];
                bf16x4_t p = {(bf16_t)v.x, (bf16_t)v.y, (bf16_t)v.z, (bf16_t)v.w};
                *(bf16x4_t*)&msgS[e * MSG_LD + c4 * 4] = p;
            }
            const float4* er = (const float4*)(edge_attr + (size_t)eg * ED);
            #pragma unroll
            for (int it = 0; it < 2; ++it) {
                const int c2 = c * 2 + it;
                float4 v = er[c2];
                bf16x4_t p = {(bf16_t)v.x, (bf16_t)v.y, (bf16_t)v.z, (bf16_t)v.w};
                *(bf16x4_t*)&msgS[e * MSG_LD + ND + c2 * 4] = p;
            }
        }
        // no barrier: wave w staged exactly the rows (16w..16w+15) it consumes below

        // ---- GEMM1: h[16w..16w+15][0..63] = relu(msg @ W1 + b1) ----
        const int abase = (16 * w + col) * MSG_LD + kq * 8;
        bf16x8_t af0 = *(const bf16x8_t*)&msgS[abase + 0 * 32];
        bf16x8_t af1 = *(const bf16x8_t*)&msgS[abase + 1 * 32];
        bf16x8_t af2 = *(const bf16x8_t*)&msgS[abase + 2 * 32];
        f32x4_t acc[4];
        #pragma unroll
        for (int nt = 0; nt < 4; ++nt) {
            acc[nt] = (f32x4_t){0.0f, 0.0f, 0.0f, 0.0f};
            acc[nt] = __builtin_amdgcn_mfma_f32_16x16x32_bf16(af0, w1f[nt][0], acc[nt], 0, 0, 0);
            acc[nt] = __builtin_amdgcn_mfma_f32_16x16x32_bf16(af1, w1f[nt][1], acc[nt], 0, 0, 0);
            acc[nt] = __builtin_amdgcn_mfma_f32_16x16x32_bf16(af2, w1f[nt][2], acc[nt], 0, 0, 0);
        }
        // epilogue: bias+relu -> hS (C/D layout: row = (lane>>4)*4 + reg, col = lane&15)
        #pragma unroll
        for (int nt = 0; nt < 4; ++nt)
            #pragma unroll
            for (int r = 0; r < 4; ++r)
                hS[(16 * w + 4 * kq + r) * H_LD + col + 16 * nt] =
                    (bf16_t)fmaxf(acc[nt][r] + b1r[nt], 0.0f);

        // ---- GEMM2: m = relu(h @ W2 + b2) (same-wave RAW on hS, lgkmcnt-ordered) ----
        const int hbase = (16 * w + col) * H_LD + kq * 8;
        bf16x8_t ah0 = *(const bf16x8_t*)&hS[hbase + 0 * 32];
        bf16x8_t ah1 = *(const bf16x8_t*)&hS[hbase + 1 * 32];
        f32x4_t acc2[4];
        #pragma unroll
        for (int nt = 0; nt < 4; ++nt) {
            acc2[nt] = (f32x4_t){0.0f, 0.0f, 0.0f, 0.0f};
            acc2[nt] = __builtin_amdgcn_mfma_f32_16x16x32_bf16(ah0, w2f[nt][0], acc2[nt], 0, 0, 0);
            acc2[nt] = __builtin_amdgcn_mfma_f32_16x16x32_bf16(ah1, w2f[nt][1], acc2[nt], 0, 0, 0);
        }

        __syncthreads();   // all waves done reading msgS/hS before Mt overwrite
        #pragma unroll
        for (int nt = 0; nt < 4; ++nt)
            #pragma unroll
            for (int r = 0; r < 4; ++r)
                Mt[(16 * w + 4 * kq + r) * MT_LD + col + 16 * nt] =
                    fmaxf(acc2[nt][r] + b2r[nt], 0.0f);
        __syncthreads();

        // ---- segmented run-merge scatter: lane = col, wave = its own 16-row window ----
        {
            const int c  = lane;
            const int r0 = w * 16;
            int cur = dstl[r0];
            float s = 0.0f;
            #pragma unroll 4
            for (int r = r0; r < r0 + 16; ++r) {
                const int d = dstl[r];
                if (d != cur) {
                    atomicAdd(&out_sum[(size_t)cur * ND + c], s);
                    s = 0.0f; cur = d;
                }
                s += Mt[r * MT_LD + c];
            }
            atomicAdd(&out_sum[(size_t)cur * ND + c], s);
        }
    }
}

// ---------------- K5: finalize out = sum/max(cnt,1) + x ----------------
__global__ void finalize_kernel(const float* __restrict__ x,
                                const int* __restrict__ cnt,
                                float* __restrict__ out)
{
    int i = blockIdx.x * blockDim.x + threadIdx.x;
    int stride = gridDim.x * blockDim.x;
    const int total4 = NODES * ND / 4;
    for (int idx = i; idx < total4; idx += stride) {
        const int n = idx / (ND / 4);
        const float inv = 1.0f / fmaxf((float)cnt[n], 1.0f);
        float4 s = ((const float4*)out)[idx];
        float4 xv = ((const float4*)x)[idx];
        float4 r;
        r.x = s.x * inv + xv.x;
        r.y = s.y * inv + xv.y;
        r.z = s.z * inv + xv.z;
        r.w = s.w * inv + xv.w;
        ((float4*)out)[idx] = r;
    }
}

extern "C" void kernel_launch(void* const* d_in, const int* in_sizes, int n_in,
                              void* d_out, int out_size, void* d_ws, size_t ws_size,
                              hipStream_t stream) {
    const float* x  = (const float*)d_in[0];
    const int*   ei = (const int*)d_in[1];     // int64 in reference -> int32 on device
    const float* ea = (const float*)d_in[2];
    const float* W1 = (const float*)d_in[3];
    const float* b1 = (const float*)d_in[4];
    const float* W2 = (const float*)d_in[5];
    const float* b2 = (const float*)d_in[6];
    float* out = (float*)d_out;

    // d_ws layout (ints): cnt[N] | offs[N+1] | cursor[N] | perm[E] | dsts[E]
    int* cnt    = (int*)d_ws;
    int* offs   = cnt + NODES;
    int* cursor = offs + NODES + 1;
    int* perm   = cursor + NODES;
    int* dsts   = perm + NEDGE;

    hipLaunchKernelGGL(zero_kernel, dim3(2048), dim3(256), 0, stream, out, cnt);
    hipLaunchKernelGGL(hist_kernel, dim3(2048), dim3(256), 0, stream, ei, cnt);
    hipLaunchKernelGGL(scan_kernel, dim3(1), dim3(SCAN_T), 0, stream, cnt, offs, cursor);
    hipLaunchKernelGGL(bucket_kernel, dim3(2048), dim3(256), 0, stream, ei, cursor, perm, dsts);
    hipLaunchKernelGGL(edge_mlp_mfma, dim3(512), dim3(256), 0, stream,
                       x, ea, W1, b1, W2, b2, perm, dsts, out);
    hipLaunchKernelGGL(finalize_kernel, dim3(1600), dim3(256), 0, stream, x, cnt, out);
}

// Round 5
// 350.989 us; speedup vs baseline: 4.2871x; 1.3365x over previous
//
#include <hip/hip_runtime.h>

// Problem constants (match reference setup_inputs)
#define NODES 50000
#define NEDGE 1600000
#define ND 64      // NODE_DIM
#define ED 32      // EDGE_DIM
#define HID 64     // HIDDEN
#define IN_DIM 96  // ND + ED

#define TILE_E 64
#define MSG_LD 104   // bf16 elems/row: 96+8 pad -> 208 B rows (16B aligned, 2-way banks on b128)
#define H_LD   72    // bf16 elems/row: 64+8 pad -> 144 B rows
#define MT_LD  65    // f32 elems/row for m-tile (odd -> conflict-free column reads)

typedef __bf16 bf16_t;
typedef __bf16 bf16x4_t __attribute__((ext_vector_type(4)));
typedef __bf16 bf16x8_t __attribute__((ext_vector_type(8)));
typedef float  f32x4_t  __attribute__((ext_vector_type(4)));

#define SCAN_B 256
#define SCAN_NBLK ((NODES + SCAN_B - 1) / SCAN_B)   // 196

// ---------------- K0: zero out accumulator + counts ----------------
__global__ void zero_kernel(float* __restrict__ out, int* __restrict__ cnt) {
    int i = blockIdx.x * blockDim.x + threadIdx.x;
    int stride = gridDim.x * blockDim.x;
    const int total = NODES * ND;
    for (int idx = i; idx < total; idx += stride) out[idx] = 0.0f;
    for (int idx = i; idx < NODES; idx += stride) cnt[idx] = 0;
}

// ---------------- K1: histogram of dst ----------------
__global__ void hist_kernel(const int* __restrict__ ei, int* __restrict__ cnt) {
    int i = blockIdx.x * blockDim.x + threadIdx.x;
    int stride = gridDim.x * blockDim.x;
    for (int e = i; e < NEDGE; e += stride)
        atomicAdd(&cnt[ei[NEDGE + e]], 1);
}

// ---------------- K2a: per-block partial sums of cnt ----------------
__global__ void scan_sum_kernel(const int* __restrict__ cnt, int* __restrict__ bsum) {
    __shared__ int sh[SCAN_B];
    const int t = threadIdx.x, b = blockIdx.x;
    const int i = b * SCAN_B + t;
    sh[t] = (i < NODES) ? cnt[i] : 0;
    __syncthreads();
    for (int d = SCAN_B / 2; d > 0; d >>= 1) {
        if (t < d) sh[t] += sh[t + d];
        __syncthreads();
    }
    if (t == 0) bsum[b] = sh[0];
}

// ---------------- K2b: exclusive scan of 196 block sums (1 tiny block) ----------------
__global__ void scan_top_kernel(int* __restrict__ bsum) {
    __shared__ int sh[SCAN_B];
    const int t = threadIdx.x;
    sh[t] = (t < SCAN_NBLK) ? bsum[t] : 0;
    __syncthreads();
    for (int d = 1; d < SCAN_B; d <<= 1) {
        int v = (t >= d) ? sh[t - d] : 0;
        __syncthreads();
        sh[t] += v;
        __syncthreads();
    }
    if (t < SCAN_NBLK) bsum[t] = sh[t] - ((t < SCAN_NBLK) ? 0 : 0) - ((t >= 0) ? ((t == 0) ? sh[0] : sh[t] - sh[t - 1]) : 0) + ((t == 0) ? 0 : 0);
    // exclusive = inclusive - own value; own value = (t==0)? sh[0] : sh[t]-sh[t-1]
    // simplify: exclusive[t] = (t==0) ? 0 : sh[t-1]
    if (t < SCAN_NBLK) bsum[t] = (t == 0) ? 0 : sh[t - 1];
}

// ---------------- K2c: fill cursor = global exclusive prefix of cnt ----------------
__global__ void scan_fill_kernel(const int* __restrict__ cnt, const int* __restrict__ bsum,
                                 int* __restrict__ cursor) {
    __shared__ int sh[SCAN_B];
    const int t = threadIdx.x, b = blockIdx.x;
    const int i = b * SCAN_B + t;
    int v = (i < NODES) ? cnt[i] : 0;
    sh[t] = v;
    __syncthreads();
    // Hillis-Steele inclusive scan
    for (int d = 1; d < SCAN_B; d <<= 1) {
        int u = (t >= d) ? sh[t - d] : 0;
        __syncthreads();
        sh[t] += u;
        __syncthreads();
    }
    if (i < NODES) cursor[i] = bsum[b] + sh[t] - v;   // exclusive
}

// ---------------- K3: bucket-scatter edge ids (CSR perm, packed int2) ----------------
__global__ void bucket_kernel(const int* __restrict__ ei, int* __restrict__ cursor,
                              int2* __restrict__ pd) {
    int i = blockIdx.x * blockDim.x + threadIdx.x;
    int stride = gridDim.x * blockDim.x;
    for (int e = i; e < NEDGE; e += stride) {
        int d = ei[NEDGE + e];
        int pos = atomicAdd(&cursor[d], 1);
        pd[pos] = make_int2(e, d);
    }
}

// ---------------- K4: per-edge MLP via bf16 MFMA (64-edge tiles, CSR order) ----------------
// Wave-private tile rows: wave w owns edges 16w..16w+15 of each tile.
__global__ __launch_bounds__(256, 2)
void edge_mlp_mfma(const float* __restrict__ x,
                   const float* __restrict__ edge_attr,
                   const float* __restrict__ W1, const float* __restrict__ b1,
                   const float* __restrict__ W2, const float* __restrict__ b2,
                   const int2* __restrict__ pd,
                   float* __restrict__ out_sum)
{
    constexpr int SMEM_MAIN = TILE_E * MSG_LD * 2 + TILE_E * H_LD * 2; // 22528 B
    constexpr int SMEM_MT   = TILE_E * MT_LD * 4;                      // 16640 B
    __shared__ __align__(16) char smem[SMEM_MAIN > SMEM_MT ? SMEM_MAIN : SMEM_MT];
    __shared__ int dstl[TILE_E];

    bf16_t* msgS = (bf16_t*)smem;                               // [64][MSG_LD]
    bf16_t* hS   = (bf16_t*)(smem + TILE_E * MSG_LD * 2);       // [64][H_LD]
    float*  Mt   = (float*)smem;                                // [64][MT_LD] (scatter phase)

    const int t    = threadIdx.x;
    const int lane = t & 63;
    const int w    = t >> 6;         // wave id 0..3
    const int col  = lane & 15;      // MFMA col / A-row selector
    const int kq   = lane >> 4;      // 0..3: k-quarter

    // ---- one-time: transpose W1,W2 into LDS (bf16) ----
    for (int i = t; i < IN_DIM * HID / 4; i += 256) {
        float4 v = ((const float4*)W1)[i];
        int k = i >> 4, j4 = (i & 15) * 4;      // W1[k][j4..j4+3]
        msgS[(j4 + 0) * MSG_LD + k] = (bf16_t)v.x;
        msgS[(j4 + 1) * MSG_LD + k] = (bf16_t)v.y;
        msgS[(j4 + 2) * MSG_LD + k] = (bf16_t)v.z;
        msgS[(j4 + 3) * MSG_LD + k] = (bf16_t)v.w;
    }
    for (int i = t; i < HID * ND / 4; i += 256) {
        float4 v = ((const float4*)W2)[i];
        int k = i >> 4, j4 = (i & 15) * 4;
        hS[(j4 + 0) * H_LD + k] = (bf16_t)v.x;
        hS[(j4 + 1) * H_LD + k] = (bf16_t)v.y;
        hS[(j4 + 2) * H_LD + k] = (bf16_t)v.z;
        hS[(j4 + 3) * H_LD + k] = (bf16_t)v.w;
    }
    __syncthreads();

    // ---- hoist loop-invariant B-fragments + biases to registers ----
    bf16x8_t w1f[4][3];   // [ntile][kstep]
    bf16x8_t w2f[4][2];
    float b1r[4], b2r[4];
    #pragma unroll
    for (int nt = 0; nt < 4; ++nt) {
        const int cn = col + 16 * nt;
        b1r[nt] = b1[cn];
        b2r[nt] = b2[cn];
        #pragma unroll
        for (int kk = 0; kk < 3; ++kk)
            w1f[nt][kk] = *(const bf16x8_t*)&msgS[cn * MSG_LD + kk * 32 + kq * 8];
        #pragma unroll
        for (int kk = 0; kk < 2; ++kk)
            w2f[nt][kk] = *(const bf16x8_t*)&hS[cn * H_LD + kk * 32 + kq * 8];
    }
    __syncthreads();   // weights consumed; smem free for tiles

    const int ntiles = NEDGE / TILE_E;   // 25000
    for (int tile = blockIdx.x; tile < ntiles; tile += gridDim.x) {
        const int eb = tile * TILE_E;
        __syncthreads();   // smem + dstl free of previous tile's readers

        if (t < TILE_E) dstl[t] = pd[eb + t].y;

        // ---- stage msg tile (bf16): rows wave-private ----
        {
            const int e = t >> 2, c = t & 3;
            const int2 rec = pd[eb + e];
            const float4* xr = (const float4*)(x + (size_t)rec.y * ND);
            #pragma unroll
            for (int it = 0; it < 4; ++it) {
                const int c4 = c + it * 4;
                float4 v = xr[c4];
                bf16x4_t p = {(bf16_t)v.x, (bf16_t)v.y, (bf16_t)v.z, (bf16_t)v.w};
                *(bf16x4_t*)&msgS[e * MSG_LD + c4 * 4] = p;
            }
            const float4* er = (const float4*)(edge_attr + (size_t)rec.x * ED);
            #pragma unroll
            for (int it = 0; it < 2; ++it) {
                const int c2 = c * 2 + it;
                float4 v = er[c2];
                bf16x4_t p = {(bf16_t)v.x, (bf16_t)v.y, (bf16_t)v.z, (bf16_t)v.w};
                *(bf16x4_t*)&msgS[e * MSG_LD + ND + c2 * 4] = p;
            }
        }
        // no barrier: wave w staged exactly the rows (16w..16w+15) it consumes below

        // ---- GEMM1: h[16w..16w+15][0..63] = relu(msg @ W1 + b1) ----
        const int abase = (16 * w + col) * MSG_LD + kq * 8;
        bf16x8_t af0 = *(const bf16x8_t*)&msgS[abase + 0 * 32];
        bf16x8_t af1 = *(const bf16x8_t*)&msgS[abase + 1 * 32];
        bf16x8_t af2 = *(const bf16x8_t*)&msgS[abase + 2 * 32];
        f32x4_t acc[4];
        #pragma unroll
        for (int nt = 0; nt < 4; ++nt) {
            acc[nt] = (f32x4_t){0.0f, 0.0f, 0.0f, 0.0f};
            acc[nt] = __builtin_amdgcn_mfma_f32_16x16x32_bf16(af0, w1f[nt][0], acc[nt], 0, 0, 0);
            acc[nt] = __builtin_amdgcn_mfma_f32_16x16x32_bf16(af1, w1f[nt][1], acc[nt], 0, 0, 0);
            acc[nt] = __builtin_amdgcn_mfma_f32_16x16x32_bf16(af2, w1f[nt][2], acc[nt], 0, 0, 0);
        }
        #pragma unroll
        for (int nt = 0; nt < 4; ++nt)
            #pragma unroll
            for (int r = 0; r < 4; ++r)
                hS[(16 * w + 4 * kq + r) * H_LD + col + 16 * nt] =
                    (bf16_t)fmaxf(acc[nt][r] + b1r[nt], 0.0f);

        // ---- GEMM2: m = relu(h @ W2 + b2) (same-wave RAW on hS, lgkmcnt-ordered) ----
        const int hbase = (16 * w + col) * H_LD + kq * 8;
        bf16x8_t ah0 = *(const bf16x8_t*)&hS[hbase + 0 * 32];
        bf16x8_t ah1 = *(const bf16x8_t*)&hS[hbase + 1 * 32];
        f32x4_t acc2[4];
        #pragma unroll
        for (int nt = 0; nt < 4; ++nt) {
            acc2[nt] = (f32x4_t){0.0f, 0.0f, 0.0f, 0.0f};
            acc2[nt] = __builtin_amdgcn_mfma_f32_16x16x32_bf16(ah0, w2f[nt][0], acc2[nt], 0, 0, 0);
            acc2[nt] = __builtin_amdgcn_mfma_f32_16x16x32_bf16(ah1, w2f[nt][1], acc2[nt], 0, 0, 0);
        }

        __syncthreads();   // all waves done reading msgS/hS before Mt overwrite
        #pragma unroll
        for (int nt = 0; nt < 4; ++nt)
            #pragma unroll
            for (int r = 0; r < 4; ++r)
                Mt[(16 * w + 4 * kq + r) * MT_LD + col + 16 * nt] =
                    fmaxf(acc2[nt][r] + b2r[nt], 0.0f);
        __syncthreads();

        // ---- segmented run-merge scatter: lane = col, wave = its own 16-row window ----
        {
            const int c  = lane;
            const int r0 = w * 16;
            int cur = dstl[r0];
            float s = 0.0f;
            #pragma unroll 4
            for (int r = r0; r < r0 + 16; ++r) {
                const int d = dstl[r];
                if (d != cur) {
                    atomicAdd(&out_sum[(size_t)cur * ND + c], s);
                    s = 0.0f; cur = d;
                }
                s += Mt[r * MT_LD + c];
            }
            atomicAdd(&out_sum[(size_t)cur * ND + c], s);
        }
    }
}

// ---------------- K5: finalize out = sum/max(cnt,1) + x ----------------
__global__ void finalize_kernel(const float* __restrict__ x,
                                const int* __restrict__ cnt,
                                float* __restrict__ out)
{
    int i = blockIdx.x * blockDim.x + threadIdx.x;
    int stride = gridDim.x * blockDim.x;
    const int total4 = NODES * ND / 4;
    for (int idx = i; idx < total4; idx += stride) {
        const int n = idx / (ND / 4);
        const float inv = 1.0f / fmaxf((float)cnt[n], 1.0f);
        float4 s = ((const float4*)out)[idx];
        float4 xv = ((const float4*)x)[idx];
        float4 r;
        r.x = s.x * inv + xv.x;
        r.y = s.y * inv + xv.y;
        r.z = s.z * inv + xv.z;
        r.w = s.w * inv + xv.w;
        ((float4*)out)[idx] = r;
    }
}

extern "C" void kernel_launch(void* const* d_in, const int* in_sizes, int n_in,
                              void* d_out, int out_size, void* d_ws, size_t ws_size,
                              hipStream_t stream) {
    const float* x  = (const float*)d_in[0];
    const int*   ei = (const int*)d_in[1];     // int64 in reference -> int32 on device
    const float* ea = (const float*)d_in[2];
    const float* W1 = (const float*)d_in[3];
    const float* b1 = (const float*)d_in[4];
    const float* W2 = (const float*)d_in[5];
    const float* b2 = (const float*)d_in[6];
    float* out = (float*)d_out;

    // d_ws layout (ints): cnt[N] | cursor[N] | pd[2E] | bsum[256]
    int*  cnt    = (int*)d_ws;
    int*  cursor = cnt + NODES;
    int2* pd     = (int2*)(cursor + NODES);
    int*  bsum   = (int*)(pd + NEDGE);

    hipLaunchKernelGGL(zero_kernel, dim3(2048), dim3(256), 0, stream, out, cnt);
    hipLaunchKernelGGL(hist_kernel, dim3(2048), dim3(256), 0, stream, ei, cnt);
    hipLaunchKernelGGL(scan_sum_kernel, dim3(SCAN_NBLK), dim3(SCAN_B), 0, stream, cnt, bsum);
    hipLaunchKernelGGL(scan_top_kernel, dim3(1), dim3(SCAN_B), 0, stream, bsum);
    hipLaunchKernelGGL(scan_fill_kernel, dim3(SCAN_NBLK), dim3(SCAN_B), 0, stream, cnt, bsum, cursor);
    hipLaunchKernelGGL(bucket_kernel, dim3(2048), dim3(256), 0, stream, ei, cursor, pd);
    hipLaunchKernelGGL(edge_mlp_mfma, dim3(1536), dim3(256), 0, stream,
                       x, ea, W1, b1, W2, b2, pd, out);
    hipLaunchKernelGGL(finalize_kernel, dim3(1600), dim3(256), 0, stream, x, cnt, out);
}